// Round 3
// baseline (1030.948 us; speedup 1.0000x reference)
//
#include <hip/hip_runtime.h>
#include <hip/hip_bf16.h>
#include <stdint.h>

// out[b,o] = sum_i (bw[o,i] + dwb[o*IN+i] + sum_k z[b,k] dwW[o*IN+i,k]) x[b,i]
//            + bbias[o] + dbb[o] + sum_k z[b,k] dbW[o,k]
// Big term as GEMM: out_big[b,o] = sum_kk y[b,kk] dwW[o,kk], y[b,i*128+k]=x[b,i]z[b,k].
// R3 design: NO LDS, NO barriers, NO atomics. Waves stream dwW global->VGPR,
// cvt fp32->bf16 in-register, MFMA 16x16x32, store split-K partials to d_ws,
// separate reduce kernel. HBM floor: 512 MB dwW + ~40 MB partials ~ 88 us.

#define IN_N  1024
#define OUT_N 1024
#define ZD_N  128
#define KK    (IN_N * ZD_N)   // 131072
#define KSPLIT 64
#define KSPAN  (KK / KSPLIT)  // 2048

typedef __attribute__((ext_vector_type(8))) short s16x8;  // 8 bf16 = 4 VGPRs
typedef __attribute__((ext_vector_type(4))) float f32x4;

union BF8 { s16x8 v; __hip_bfloat162 b[4]; };

// ---------------- small part: writes every out element (fp32) ---------------------------
__global__ __launch_bounds__(256) void init_small(
    const float* __restrict__ x, const float* __restrict__ z,
    const float* __restrict__ bw, const float* __restrict__ dwb,
    const float* __restrict__ bbias, const float* __restrict__ dbW,
    const float* __restrict__ dbb, float* __restrict__ out)
{
    const int tid = threadIdx.x;
    const int b   = tid & 127;
    const int o   = blockIdx.x * 2 + (tid >> 7);   // 512 blocks x 2 outputs

    float acc = bbias[o] + dbb[o];

    // delta_b = z @ dbW^T   (dbW row o wave-uniform, z gathered)
    const float* zrow = z + (size_t)b * ZD_N;
    const float* dr   = dbW + (size_t)o * ZD_N;
    for (int k = 0; k < ZD_N; k += 4) {
        float4 zv = *(const float4*)(zrow + k);
        float4 dv = *(const float4*)(dr + k);
        acc += zv.x * dv.x + zv.y * dv.y + zv.z * dv.z + zv.w * dv.w;
    }
    // x @ (bw + dwb_view)^T  (fp32 exact)
    const float* xrow = x  + (size_t)b * IN_N;
    const float* wr   = bw + (size_t)o * IN_N;
    const float* vr   = dwb + (size_t)o * IN_N;
    for (int i = 0; i < IN_N; i += 4) {
        float4 xv = *(const float4*)(xrow + i);
        float4 wv = *(const float4*)(wr + i);
        float4 vv = *(const float4*)(vr + i);
        acc += xv.x * (wv.x + vv.x) + xv.y * (wv.y + vv.y)
             + xv.z * (wv.z + vv.z) + xv.w * (wv.w + vv.w);
    }
    out[(size_t)b * OUT_N + o] = acc;
}

// ---------------- big GEMM: barrier-free streaming, split-K partials to ws ---------------
__global__ __launch_bounds__(256, 2) void hyper_gemm(
    const float* __restrict__ x,    // [128,1024]
    const float* __restrict__ z,    // [128,128]
    const float* __restrict__ dwW,  // [1024,131072] row-major
    float* __restrict__ ws)         // [KSPLIT][128][1024] fp32 partials
{
    const int tid  = threadIdx.x;
    const int lane = tid & 63;
    const int w    = tid >> 6;
    const int wm   = (w & 1) * 64;   // wave 2x2 over 128(m) x 128(n)
    const int wn   = (w >> 1) * 64;
    const int q    = lane >> 4;
    const int l16  = lane & 15;

    const int nb = blockIdx.x & 7;        // 8 n-tiles
    const int ks = blockIdx.x >> 3;       // 64 k-splits
    const int n0 = nb * 128;
    const long long kk0 = (long long)ks * KSPAN;

    f32x4 acc[4][4];
#pragma unroll
    for (int mt = 0; mt < 4; ++mt)
#pragma unroll
        for (int nt = 0; nt < 4; ++nt) acc[mt][nt] = (f32x4)0.0f;

    // per-lane base pointers (hoisted address math)
    const float* brow[4];
    const float* zrow[4];
    const float* xrowp[4];
#pragma unroll
    for (int nt = 0; nt < 4; ++nt)
        brow[nt] = dwW + (size_t)(n0 + wn + nt * 16 + l16) * KK + kk0 + q * 8;
#pragma unroll
    for (int mt = 0; mt < 4; ++mt) {
        const int m = wm + mt * 16 + l16;
        zrow[mt]  = z + (size_t)m * ZD_N + q * 8;
        xrowp[mt] = x + (size_t)m * IN_N;
    }
    const int i0 = (int)(kk0 >> 7);

#pragma unroll 1
    for (int e = 0; e < KSPAN / 128; ++e) {   // 16 epochs of 128 kk (one x column each)
        float xv[4];
#pragma unroll
        for (int mt = 0; mt < 4; ++mt) xv[mt] = xrowp[mt][i0 + e];

#pragma unroll 1
        for (int s = 0; s < 4; ++s) {         // 4 k-steps of 32 kk
            const int off = e * 128 + s * 32;
            s16x8 bfr[4];
#pragma unroll
            for (int nt = 0; nt < 4; ++nt) {
                float4 b0 = *(const float4*)(brow[nt] + off);
                float4 b1 = *(const float4*)(brow[nt] + off + 4);
                BF8 u;
                u.b[0] = __float22bfloat162_rn(make_float2(b0.x, b0.y));
                u.b[1] = __float22bfloat162_rn(make_float2(b0.z, b0.w));
                u.b[2] = __float22bfloat162_rn(make_float2(b1.x, b1.y));
                u.b[3] = __float22bfloat162_rn(make_float2(b1.z, b1.w));
                bfr[nt] = u.v;
            }
#pragma unroll
            for (int mt = 0; mt < 4; ++mt) {
                const float* zp = zrow[mt] + s * 32;
                float4 z0 = *(const float4*)(zp);
                float4 z1 = *(const float4*)(zp + 4);
                BF8 af;
                af.b[0] = __float22bfloat162_rn(make_float2(xv[mt] * z0.x, xv[mt] * z0.y));
                af.b[1] = __float22bfloat162_rn(make_float2(xv[mt] * z0.z, xv[mt] * z0.w));
                af.b[2] = __float22bfloat162_rn(make_float2(xv[mt] * z1.x, xv[mt] * z1.y));
                af.b[3] = __float22bfloat162_rn(make_float2(xv[mt] * z1.z, xv[mt] * z1.w));
#pragma unroll
                for (int nt = 0; nt < 4; ++nt)
                    acc[mt][nt] = __builtin_amdgcn_mfma_f32_16x16x32_bf16(
                        af.v, bfr[nt], acc[mt][nt], 0, 0, 0);
            }
        }
    }

    // coalesced partial store: ws[ks][m][n0+n]; C/D layout col=l16 (n), row=q*4+r (m)
    float* wsb = ws + (size_t)ks * (128 * 1024) + n0;
#pragma unroll
    for (int mt = 0; mt < 4; ++mt) {
        const int mbase = wm + mt * 16 + q * 4;
#pragma unroll
        for (int nt = 0; nt < 4; ++nt) {
            const int n = wn + nt * 16 + l16;
#pragma unroll
            for (int r = 0; r < 4; ++r)
                wsb[(size_t)(mbase + r) * 1024 + n] = acc[mt][nt][r];
        }
    }
}

// ---------------- reduce: out += sum over k-splits -------------------------------------
__global__ __launch_bounds__(256) void reduce_out(const float* __restrict__ ws,
                                                  float* __restrict__ out)
{
    const int idx = blockIdx.x * 256 + threadIdx.x;   // 512 blocks -> 131072 threads
    float s = out[idx];
#pragma unroll
    for (int k = 0; k < KSPLIT; ++k)
        s += ws[(size_t)k * (128 * 1024) + idx];
    out[idx] = s;
}

extern "C" void kernel_launch(void* const* d_in, const int* in_sizes, int n_in,
                              void* d_out, int out_size, void* d_ws, size_t ws_size,
                              hipStream_t stream) {
    const float* x     = (const float*)d_in[0];
    const float* z     = (const float*)d_in[1];
    const float* bw    = (const float*)d_in[2];
    const float* dwW   = (const float*)d_in[3];
    const float* dwb   = (const float*)d_in[4];
    const float* bbias = (const float*)d_in[5];
    const float* dbW   = (const float*)d_in[6];
    const float* dbb   = (const float*)d_in[7];
    float* out = (float*)d_out;
    float* ws  = (float*)d_ws;    // 64 * 512 KB = 32 MB used

    hipLaunchKernelGGL(init_small, dim3(512), dim3(256), 0, stream,
                       x, z, bw, dwb, bbias, dbW, dbb, out);
    hipLaunchKernelGGL(hyper_gemm, dim3(512), dim3(256), 0, stream, x, z, dwW, ws);
    hipLaunchKernelGGL(reduce_out, dim3(512), dim3(256), 0, stream, ws, out);
}